// Round 11
// baseline (22.478 us; speedup 1.0000x reference)
//
#include <hip/hip_runtime.h>
#include <math.h>

// SMorphLayer via f16 MFMA implicit-GEMM. B=8,C=1,H=W=128,F=16,K=5 -> 124x124.
// y[b,f,oy,ox] = n1/d1 + n2/d2 + bias[f], per-tap features (f16)
//   c0=E=e^p, c1=pE, c2=I=e^-p, c3=pI
// weights W[k=(tap*4+c)][n]: n 0..15=n1_f, 16..31=d1_f, 32..47=n2_f, 48..63=d2_f
//   n1: c0->k1*e1, c1->e1 | d1: c0->e1 | n2: c2->k2*e2, c3->-e2 | d2: c2->e2
// K=100 padded to 128 with zeros.
//
// Round-10: root cause of rounds 7-9 was the weight-scatter guard
// `if (tid < 400)` with only 256 threads -> taps j=16..24 never scattered
// (j = tid>>4 <= 15). Round-9's diagnostic confirmed the MFMA layout itself
// is correct on HW (flag add=0). Fix: grid-stride scatter loop over 400.
// f16 chosen over bf16 for 8x quantization margin (both paths proven
// functionally identical by rounds 7/8 matching bit-for-bit).

#define Bn 8
#define Fn 16
#define Hn 128
#define Wn 128
#define OHn 124
#define OWn 124
#define FR 5
#define FC 68

typedef _Float16 f16;
typedef __attribute__((ext_vector_type(8))) _Float16 f16x8;
typedef __attribute__((ext_vector_type(4))) _Float16 f16x4;
typedef __attribute__((ext_vector_type(4))) float f4_t;

__global__ __launch_bounds__(256) void smorph_mfma(
    const float* __restrict__ x, const float* __restrict__ k1,
    const float* __restrict__ k2, const float* __restrict__ bias,
    float* __restrict__ out) {
  __shared__ __align__(16) f16 Bt[64][128];       // Bt[n][k] = W[k][n], 16 KB
  __shared__ __align__(16) f16 At[64][128];       // At[px][k] im2col, 16 KB
  __shared__ __align__(16) f16 feat[FR * FC * 4]; // {E,pE,I,pI}, 2720 B

  const int tid = threadIdx.x;
  const int b = blockIdx.z;
  const int oy = blockIdx.y;                    // one output row per block
  const int ox0 = blockIdx.x ? (OWn - 64) : 0;  // strips {0,60}; overlap cols
                                                // written with identical values

  // ---- phase 1: explicit zero of BOTH tiles ----
  {
    const f16x8 z = {0, 0, 0, 0, 0, 0, 0, 0};
    for (int i = tid; i < 64 * 128 / 8; i += 256) {
      ((f16x8*)Bt)[i] = z;
      ((f16x8*)At)[i] = z;
    }
  }
  __syncthreads();

  // ---- phase 2: scatter weights (ALL 400 (f,j) pairs!) + stage features ----
  for (int i = tid; i < 400; i += 256) {   // i = j*16 + f, j 0..24, f 0..15
    const int f = i & 15, j = i >> 4;
    const float a = k1[f * 25 + j], c = k2[f * 25 + j];
    const float e1 = __expf(a), e2 = __expf(c);
    Bt[f     ][j * 4 + 0] = (f16)(a * e1);
    Bt[f     ][j * 4 + 1] = (f16)e1;
    Bt[16 + f][j * 4 + 0] = (f16)e1;
    Bt[32 + f][j * 4 + 2] = (f16)(c * e2);
    Bt[32 + f][j * 4 + 3] = (f16)(-e2);
    Bt[48 + f][j * 4 + 2] = (f16)e2;
  }
  // feature rows oy..oy+4, cols ox0..ox0+67 (always in-bounds)
  const float* xb = x + (b * Hn + oy) * Wn + ox0;
  for (int i = tid; i < FR * FC; i += 256) {
    const int r = i / FC, cpos = i % FC;
    const float p = xb[r * Wn + cpos];
    const float E = __expf(p), I = __expf(-p);
    f16x4 v;
    v[0] = (f16)E; v[1] = (f16)(p * E); v[2] = (f16)I; v[3] = (f16)(p * I);
    *(f16x4*)&feat[i * 4] = v;
  }
  __syncthreads();

  // ---- phase 3: im2col At[px][t*4+c] (t<25 only; K-tail stays zero) ----
  for (int q = tid; q < 64 * 25; q += 256) {
    const int px = q / 25, t = q - px * 25;
    const int kh = t / 5, kw = t - kh * 5;
    const f16x4 v = *(const f16x4*)&feat[(kh * FC + px + kw) * 4];
    *(f16x4*)&At[px][t * 4] = v;
  }
  __syncthreads();

  // ---- phase 4: MFMA ----
  const int lane = tid & 63, wv = tid >> 6;
  const int mh = lane & 15;       // A row (pixel) on loads; D col (chan) on out
  const int half = lane >> 4;

  f4_t acc0 = {0,0,0,0}, acc1 = {0,0,0,0}, acc2 = {0,0,0,0}, acc3 = {0,0,0,0};
#pragma unroll
  for (int kk = 0; kk < 4; ++kk) {
    const f16x8 A  = *(const f16x8*)&At[wv * 16 + mh][kk * 32 + half * 8];
    const f16x8 B0 = *(const f16x8*)&Bt[ 0 + mh][kk * 32 + half * 8];
    const f16x8 B1 = *(const f16x8*)&Bt[16 + mh][kk * 32 + half * 8];
    const f16x8 B2 = *(const f16x8*)&Bt[32 + mh][kk * 32 + half * 8];
    const f16x8 B3 = *(const f16x8*)&Bt[48 + mh][kk * 32 + half * 8];
    acc0 = __builtin_amdgcn_mfma_f32_16x16x32_f16(A, B0, acc0, 0, 0, 0);
    acc1 = __builtin_amdgcn_mfma_f32_16x16x32_f16(A, B1, acc1, 0, 0, 0);
    acc2 = __builtin_amdgcn_mfma_f32_16x16x32_f16(A, B2, acc2, 0, 0, 0);
    acc3 = __builtin_amdgcn_mfma_f32_16x16x32_f16(A, B3, acc3, 0, 0, 0);
  }

  // ---- epilogue: lane holds n1,d1,n2,d2 for chan mh, pixels half*4+0..3 ----
  const float bv = bias[mh];
  const int pxcol = ox0 + wv * 16 + half * 4;
  f4_t o;
#pragma unroll
  for (int j = 0; j < 4; ++j)
    o[j] = __fdividef(acc0[j], acc1[j]) + __fdividef(acc2[j], acc3[j]) + bv;
  *(f4_t*)&out[((b * Fn + mh) * OHn + oy) * OWn + pxcol] = o;
}

extern "C" void kernel_launch(void* const* d_in, const int* in_sizes, int n_in,
                              void* d_out, int out_size, void* d_ws, size_t ws_size,
                              hipStream_t stream) {
  const float* x    = (const float*)d_in[0];
  const float* k1   = (const float*)d_in[1];
  const float* k2   = (const float*)d_in[2];
  const float* bias = (const float*)d_in[3];
  float* out = (float*)d_out;

  dim3 grid(2, OHn, Bn);  // (2, 124, 8) = 1984 blocks
  smorph_mfma<<<grid, 256, 0, stream>>>(x, k1, k2, bias, out);
}

// Round 12
// 13.333 us; speedup vs baseline: 1.6859x; 1.6859x over previous
//
#include <hip/hip_runtime.h>
#include <math.h>

// SMorphLayer via f16 MFMA implicit-GEMM, minimal-scaffold form.
// B=8,C=1,H=W=128,F=16,K=5 -> 124x124.
// y[b,f,oy,ox] = n1/d1 + n2/d2 + bias[f]; per-tap features {E,pE,I,pI} (f16);
// weights W[k=tap*4+c][n]: n 0..15=n1 | 16..31=d1 | 32..47=n2 | 48..63=d2.
// K=100 (tail k>=100 never touched: A reads zero-slot there, Bt tail zeroed).
//
// Round-11 structure (round-7 A-path, exonerated by the round-9 diagnostic:
// rounds 7/8 were bit-identical, bug was only the tid<400 scatter guard):
//  * no im2col tile, no full LDS zeroing, ONE barrier
//  * OY=4 output rows per block; B-fragments hoisted to 64 VGPRs once
//  * LDS ~20.7KB -> 7 blocks/CU; 496-block grid fully co-resident

#define Bn 8
#define Fn 16
#define Hn 128
#define Wn 128
#define OHn 124
#define OWn 124
#define OY 4
#define FR (OY + 4)          // feature rows staged = 8
#define FC 68                // feature cols staged
#define ZSLOT (FR * FC * 4)  // zero-slot element index in feat

typedef _Float16 f16;
typedef __attribute__((ext_vector_type(8))) _Float16 f16x8;
typedef __attribute__((ext_vector_type(4))) _Float16 f16x4;
typedef __attribute__((ext_vector_type(4))) float f4_t;

__global__ __launch_bounds__(256) void smorph_mfma(
    const float* __restrict__ x, const float* __restrict__ k1,
    const float* __restrict__ k2, const float* __restrict__ bias,
    float* __restrict__ out) {
  __shared__ __align__(16) f16 Bt[64][128];        // Bt[n][k] = W[k][n], 16 KB
  __shared__ __align__(16) f16 feat[ZSLOT + 4];    // [row][col][c] + zero slot

  const int tid = threadIdx.x;
  const int b = blockIdx.z;
  const int oy0 = blockIdx.y * OY;
  const int ox0 = blockIdx.x ? (OWn - 64) : 0;  // strips {0,60}; overlap cols
                                                // written with identical values

  // ---- stage weights: 4 b64 rows per (f,j) = full k<100 coverage ----
  for (int i = tid; i < 400; i += 256) {   // i = j*16 + f
    const int f = i & 15, j = i >> 4;
    const float a = k1[f * 25 + j], c = k2[f * 25 + j];
    const float e1 = __expf(a), e2 = __expf(c);
    f16x4 r0; r0[0] = (f16)(a * e1); r0[1] = (f16)e1; r0[2] = (f16)0; r0[3] = (f16)0;
    f16x4 r1; r1[0] = (f16)e1;       r1[1] = (f16)0;  r1[2] = (f16)0; r1[3] = (f16)0;
    f16x4 r2; r2[0] = (f16)0; r2[1] = (f16)0; r2[2] = (f16)(c * e2); r2[3] = (f16)(-e2);
    f16x4 r3; r3[0] = (f16)0; r3[1] = (f16)0; r3[2] = (f16)e2;       r3[3] = (f16)0;
    *(f16x4*)&Bt[f     ][j * 4] = r0;
    *(f16x4*)&Bt[16 + f][j * 4] = r1;
    *(f16x4*)&Bt[32 + f][j * 4] = r2;
    *(f16x4*)&Bt[48 + f][j * 4] = r3;
  }
  // zero the K-tail (cols 100..127) so garbage can't meet a NaN pattern
  {
    const f16x4 z = {0, 0, 0, 0};
    for (int i = tid; i < 64 * 7; i += 256) {        // 7 b64 per row
      const int row = i / 7, c8 = i % 7;
      *(f16x4*)&Bt[row][100 + c8 * 4] = z;
    }
    if (tid == 0) *(f16x4*)&feat[ZSLOT] = z;
  }
  // ---- stage features: rows oy0..oy0+7, cols ox0..ox0+67 (in-bounds) ----
  const float* xb = x + (b * Hn + oy0) * Wn + ox0;
  for (int i = tid; i < FR * FC; i += 256) {
    const int r = i / FC, cpos = i % FC;
    const float p = xb[r * Wn + cpos];
    const float E = __expf(p), I = __expf(-p);
    f16x4 v;
    v[0] = (f16)E; v[1] = (f16)(p * E); v[2] = (f16)I; v[3] = (f16)(p * I);
    *(f16x4*)&feat[i * 4] = v;
  }
  __syncthreads();  // the only barrier

  // ---- per-wave: 16 px x 64 ch x OY rows ----
  const int lane = tid & 63, wv = tid >> 6;
  const int mh = lane & 15;      // A row (pixel) in loads; D col (chan) on out
  const int half = lane >> 4;

  // hoist B fragments: Bf[kk][nt], 64 VGPRs, reused all rounds
  f16x8 Bf[4][4];
#pragma unroll
  for (int kk = 0; kk < 4; ++kk)
#pragma unroll
    for (int nt = 0; nt < 4; ++nt)
      Bf[kk][nt] = *(const f16x8*)&Bt[nt * 16 + mh][kk * 32 + half * 8];

  // A-tap element addresses (t = kk*8 + half*2 + s); -1 -> zero slot
  int taddr[8];
#pragma unroll
  for (int kk = 0; kk < 4; ++kk)
#pragma unroll
    for (int s = 0; s < 2; ++s) {
      const int t = kk * 8 + half * 2 + s;
      const int kh = t / 5, kw = t - kh * 5;
      taddr[kk * 2 + s] = (t < 25) ? (kh * FC + (wv * 16 + mh) + kw) * 4 : -1;
    }

  const float bv = bias[mh];
  const int pxcol = ox0 + wv * 16 + half * 4;

#pragma unroll 1
  for (int r = 0; r < OY; ++r) {
    const int roff = r * (FC * 4);
    f4_t acc0 = {0,0,0,0}, acc1 = {0,0,0,0}, acc2 = {0,0,0,0}, acc3 = {0,0,0,0};
#pragma unroll
    for (int kk = 0; kk < 4; ++kk) {
      const int i0 = taddr[kk * 2], i1 = taddr[kk * 2 + 1];
      const f16x4 a0 = *(const f16x4*)&feat[(i0 < 0) ? ZSLOT : i0 + roff];
      const f16x4 a1 = *(const f16x4*)&feat[(i1 < 0) ? ZSLOT : i1 + roff];
      const f16x8 A = __builtin_shufflevector(a0, a1, 0, 1, 2, 3, 4, 5, 6, 7);
      acc0 = __builtin_amdgcn_mfma_f32_16x16x32_f16(A, Bf[kk][0], acc0, 0, 0, 0);
      acc1 = __builtin_amdgcn_mfma_f32_16x16x32_f16(A, Bf[kk][1], acc1, 0, 0, 0);
      acc2 = __builtin_amdgcn_mfma_f32_16x16x32_f16(A, Bf[kk][2], acc2, 0, 0, 0);
      acc3 = __builtin_amdgcn_mfma_f32_16x16x32_f16(A, Bf[kk][3], acc3, 0, 0, 0);
    }
    f4_t o;
#pragma unroll
    for (int j = 0; j < 4; ++j)
      o[j] = __fdividef(acc0[j], acc1[j]) + __fdividef(acc2[j], acc3[j]) + bv;
    *(f4_t*)&out[((b * Fn + mh) * OHn + (oy0 + r)) * OWn + pxcol] = o;
  }
}

extern "C" void kernel_launch(void* const* d_in, const int* in_sizes, int n_in,
                              void* d_out, int out_size, void* d_ws, size_t ws_size,
                              hipStream_t stream) {
  const float* x    = (const float*)d_in[0];
  const float* k1   = (const float*)d_in[1];
  const float* k2   = (const float*)d_in[2];
  const float* bias = (const float*)d_in[3];
  float* out = (float*)d_out;

  dim3 grid(2, OHn / OY, Bn);  // (2, 31, 8) = 496 blocks, fully co-resident
  smorph_mfma<<<grid, 256, 0, stream>>>(x, k1, k2, bias, out);
}